// Round 1
// baseline (187.246 us; speedup 1.0000x reference)
//
#include <hip/hip_runtime.h>
#include <math.h>

#define NRES 22

// Select fr[d] (d in 0..7) into P via a 3-level cndmask tree.
// All fr indices are compile-time constants -> fr stays in VGPRs.
__device__ __forceinline__ void sel8(const float (&fr)[8][12], int d, float (&P)[12]) {
    const bool b0 = (d & 1) != 0;
    const bool b1 = (d & 2) != 0;
    const bool b2 = (d & 4) != 0;
#pragma unroll
    for (int k = 0; k < 12; ++k) {
        float a01 = b0 ? fr[1][k] : fr[0][k];
        float a23 = b0 ? fr[3][k] : fr[2][k];
        float a45 = b0 ? fr[5][k] : fr[4][k];
        float a67 = b0 ? fr[7][k] : fr[6][k];
        float b03 = b1 ? a23 : a01;
        float b47 = b1 ? a67 : a45;
        P[k] = b2 ? b47 : b03;
    }
}

__device__ __forceinline__ void apply_point(const float (&F)[12], float x, float y, float z,
                                            float &px, float &py, float &pz) {
    px = fmaf(F[0], x, fmaf(F[1], y, fmaf(F[2], z, F[9])));
    py = fmaf(F[3], x, fmaf(F[4], y, fmaf(F[5], z, F[10])));
    pz = fmaf(F[6], x, fmaf(F[7], y, fmaf(F[8], z, F[11])));
}

extern "C" __global__ __launch_bounds__(256)
void model_kernel(const float* __restrict__ o0,     // (N,17)
                  const float* __restrict__ o1,     // (N,3,3)
                  const float* __restrict__ pos,    // (N,3)
                  const int*   __restrict__ ssArr,  // (N,)
                  const int*   __restrict__ rtArr,  // (N,)
                  const float* __restrict__ rigT,   // (3,22,8,4,3)
                  const float* __restrict__ rigG,   // (3,22,24,3)
                  const int*   __restrict__ tdepArr,// (22,8)
                  const int*   __restrict__ rdepArr,// (22,24)
                  float* __restrict__ outR,         // (N,24,3)
                  float* __restrict__ outF,         // (N,4,3)
                  int N)
{
    const int res = blockIdx.x * 256 + threadIdx.x;
    if (res >= N) return;

    const int s  = ssArr[res];
    const int rt = rtArr[res];

    // ---- torsion cos/sin (normalize pairs) ----
    float c[7], sn[7];
    const float* o0p = o0 + (size_t)res * 17;
#pragma unroll
    for (int t = 0; t < 7; ++t) {
        float cr = o0p[2 * t], sr = o0p[2 * t + 1];
        float n2 = cr * cr + sr * sr;
        // 1/max(sqrt(n2),1e-6) == rsqrt(max(n2,1e-12))  (sqrt is monotone)
        float inv = rsqrtf(fmaxf(n2, 1e-12f));
        c[t]  = cr * inv;
        sn[t] = sr * inv;
    }

    // ---- backbone frame (Gram-Schmidt) ----
    const float* o1p = o1 + (size_t)res * 9;
    float r0x = o1p[0], r0y = o1p[1], r0z = o1p[2];
    float v1x = o1p[3], v1y = o1p[4], v1z = o1p[5];
    float t2x = o1p[6], t2y = o1p[7], t2z = o1p[8];
    float inv0 = rsqrtf(fmaxf(r0x * r0x + r0y * r0y + r0z * r0z, 1e-12f));
    float e0x = r0x * inv0, e0y = r0y * inv0, e0z = r0z * inv0;
    float d01 = e0x * v1x + e0y * v1y + e0z * v1z;
    float u1x = v1x - e0x * d01, u1y = v1y - e0y * d01, u1z = v1z - e0z * d01;
    float inv1 = rsqrtf(fmaxf(u1x * u1x + u1y * u1y + u1z * u1z, 1e-12f));
    float e1x = u1x * inv1, e1y = u1y * inv1, e1z = u1z * inv1;
    float e2x = e0y * e1z - e0z * e1y;
    float e2y = e0z * e1x - e0x * e1z;
    float e2z = e0x * e1y - e0y * e1x;
    const float* pp = pos + (size_t)res * 3;
    float btx = 0.1f * t2x + pp[0];
    float bty = 0.1f * t2y + pp[1];
    float btz = 0.1f * t2z + pp[2];

    const int sr22 = s * NRES + rt;
    const float4* T4 = (const float4*)rigT + (size_t)sr22 * 24; // 8 frames * 3 float4

    float fr[8][12];

    // frame 0 = combine(T0, [rot(cols e0,e1,e2); bt])
    {
        float4 q0 = T4[0], q1 = T4[1], q2 = T4[2];
        float T0[12] = {q0.x, q0.y, q0.z, q0.w, q1.x, q1.y, q1.z, q1.w,
                        q2.x, q2.y, q2.z, q2.w};
#pragma unroll
        for (int i = 0; i < 3; ++i) {
            float a = T0[i * 3 + 0], b = T0[i * 3 + 1], d = T0[i * 3 + 2];
            fr[0][i * 3 + 0] = a * e0x + b * e0y + d * e0z;
            fr[0][i * 3 + 1] = a * e1x + b * e1y + d * e1z;
            fr[0][i * 3 + 2] = a * e2x + b * e2y + d * e2z;
            fr[0][9 + i]     = a * btx + b * bty + d * btz + T0[9 + i];
        }
    }

    // frames 1..7 = combine(Tf, rotX(c,s)) ; translation = T_t
#pragma unroll
    for (int f = 1; f < 8; ++f) {
        float4 q0 = T4[f * 3 + 0], q1 = T4[f * 3 + 1], q2 = T4[f * 3 + 2];
        float Tf[12] = {q0.x, q0.y, q0.z, q0.w, q1.x, q1.y, q1.z, q1.w,
                        q2.x, q2.y, q2.z, q2.w};
        float cc = c[f - 1], ssn = sn[f - 1];
#pragma unroll
        for (int i = 0; i < 3; ++i) {
            fr[f][i * 3 + 0] = Tf[i * 3 + 0];
            fr[f][i * 3 + 1] = Tf[i * 3 + 1] * cc + Tf[i * 3 + 2] * ssn;
            fr[f][i * 3 + 2] = Tf[i * 3 + 2] * cc - Tf[i * 3 + 1] * ssn;
            fr[f][9 + i]     = Tf[9 + i];
        }
    }

    // ---- sequential dependency chain ----
    int tdv[8];
    {
        const int4* tdq = (const int4*)(tdepArr + rt * 8); // 32B-aligned
        int4 a = tdq[0], b = tdq[1];
        tdv[0] = a.x; tdv[1] = a.y; tdv[2] = a.z; tdv[3] = a.w;
        tdv[4] = b.x; tdv[5] = b.y; tdv[6] = b.z; tdv[7] = b.w;
    }
#pragma unroll
    for (int i = 1; i < 8; ++i) {
        float P[12];
        sel8(fr, tdv[i] & 7, P);
        float Y[12];
#pragma unroll
        for (int k = 0; k < 12; ++k) Y[k] = fr[i][k];
#pragma unroll
        for (int r = 0; r < 3; ++r) {
            float a = P[r * 3 + 0], b = P[r * 3 + 1], d = P[r * 3 + 2];
#pragma unroll
            for (int j = 0; j < 3; ++j)
                fr[i][r * 3 + j] = a * Y[j] + b * Y[3 + j] + d * Y[6 + j];
            fr[i][9 + r] = a * Y[9] + b * Y[10] + d * Y[11] + P[9 + r];
        }
    }

    // ---- atoms: 24 point transforms, 4 per chunk, float4 I/O ----
    const float4* G4  = (const float4*)rigG + (size_t)sr22 * 18; // 24*3 floats
    const int4*   RD4 = (const int4*)(rdepArr + rt * 24);        // 96B-aligned
    float4* OR4 = (float4*)(outR + (size_t)res * 72);
#pragma unroll
    for (int ck = 0; ck < 6; ++ck) {
        int4 rd = RD4[ck];
        float4 g0 = G4[ck * 3 + 0], g1 = G4[ck * 3 + 1], g2 = G4[ck * 3 + 2];
        float P[12];
        float p0x, p0y, p0z, p1x, p1y, p1z, p2x, p2y, p2z, p3x, p3y, p3z;
        sel8(fr, rd.x & 7, P); apply_point(P, g0.x, g0.y, g0.z, p0x, p0y, p0z);
        sel8(fr, rd.y & 7, P); apply_point(P, g0.w, g1.x, g1.y, p1x, p1y, p1z);
        sel8(fr, rd.z & 7, P); apply_point(P, g1.z, g1.w, g2.x, p2x, p2y, p2z);
        sel8(fr, rd.w & 7, P); apply_point(P, g2.y, g2.z, g2.w, p3x, p3y, p3z);
        OR4[ck * 3 + 0] = make_float4(p0x, p0y, p0z, p1x);
        OR4[ck * 3 + 1] = make_float4(p1y, p1z, p2x, p2y);
        OR4[ck * 3 + 2] = make_float4(p2z, p3x, p3y, p3z);
    }

    // ---- second output: opr[:,0] ----
    float4* OF4 = (float4*)(outF + (size_t)res * 12);
    OF4[0] = make_float4(fr[0][0], fr[0][1], fr[0][2], fr[0][3]);
    OF4[1] = make_float4(fr[0][4], fr[0][5], fr[0][6], fr[0][7]);
    OF4[2] = make_float4(fr[0][8], fr[0][9], fr[0][10], fr[0][11]);
}

extern "C" void kernel_launch(void* const* d_in, const int* in_sizes, int n_in,
                              void* d_out, int out_size, void* d_ws, size_t ws_size,
                              hipStream_t stream) {
    const float* o0   = (const float*)d_in[0];
    const float* o1   = (const float*)d_in[1];
    const float* pos  = (const float*)d_in[2];
    const int*   ssA  = (const int*)d_in[3];
    const int*   rtA  = (const int*)d_in[4];
    const float* rigT = (const float*)d_in[5];
    const float* rigG = (const float*)d_in[6];
    const int*   tdep = (const int*)d_in[7];
    const int*   rdep = (const int*)d_in[8];

    const int N = in_sizes[3]; // ss has N elements
    float* outR = (float*)d_out;
    float* outF = (float*)d_out + (size_t)N * 72;

    const int block = 256;
    const int grid  = (N + block - 1) / block;
    model_kernel<<<grid, block, 0, stream>>>(o0, o1, pos, ssA, rtA, rigT, rigG,
                                             tdep, rdep, outR, outF, N);
}